// Round 2
// baseline (210.784 us; speedup 1.0000x reference)
//
#include <hip/hip_runtime.h>

#define NBINS 101
#define BT 128            // block tile (pairs tile is BT x BT)
#define NTHREADS 256
#define LDK 136           // padded halves per LDS tile row (128 + 8)
#define NCOPY 32          // histogram replicas, one per lane&31

typedef _Float16 half8 __attribute__((ext_vector_type(8)));
typedef float floatx4 __attribute__((ext_vector_type(4)));

// ---------------------------------------------------------------------------
// One block per 128x128 upper-triangular tile of the similarity matrix.
// f16 MFMA (16x16x32) computes the 128x128 similarity tile; each pair is
// binned into LDS histograms laid out [2*NBINS][32 copies] so that every
// lane's atomic lands in bank (lane&31): zero bank conflicts by construction,
// max 2-way same-address serialization (lane vs lane^32).
// ---------------------------------------------------------------------------
__global__ __launch_bounds__(NTHREADS, 1)
void hist_pairs_kernel(const float* __restrict__ feats,
                       const int* __restrict__ classes,
                       float* __restrict__ g_hist,   // [2][NBINS]
                       int ntiles) {
    __shared__ __align__(16) _Float16 As[BT][LDK];
    __shared__ __align__(16) _Float16 Bs[BT][LDK];
    __shared__ float lhist[2 * NBINS][NCOPY];
    __shared__ __align__(16) int clsA[BT];
    __shared__ __align__(16) int clsB[BT];

    // blockIdx -> (ti, tj), ti <= tj, row-major over the upper triangle
    int b = blockIdx.x;
    int ti = 0, rem = b;
    while (rem >= ntiles - ti) { rem -= ntiles - ti; ++ti; }
    int tj = ti + rem;
    const int i0 = ti * BT, j0 = tj * BT;
    const int tid = threadIdx.x;

    // zero local histograms (2*101*32 floats)
    for (int t = tid; t < 2 * NBINS * NCOPY; t += NTHREADS)
        (&lhist[0][0])[t] = 0.0f;

    // stage both tiles, fp32 -> f16. thread t: row = t>>1, half-row (t&1)*64
    {
        const int row = tid >> 1;
        const int c0 = (tid & 1) * 64;
        const float* pa = &feats[(size_t)(i0 + row) * 128 + c0];
        const float* pb = &feats[(size_t)(j0 + row) * 128 + c0];
        #pragma unroll
        for (int c = 0; c < 64; c += 8) {
            float4 f0 = *(const float4*)&pa[c];
            float4 f1 = *(const float4*)&pa[c + 4];
            half8 h;
            h[0] = (_Float16)f0.x; h[1] = (_Float16)f0.y;
            h[2] = (_Float16)f0.z; h[3] = (_Float16)f0.w;
            h[4] = (_Float16)f1.x; h[5] = (_Float16)f1.y;
            h[6] = (_Float16)f1.z; h[7] = (_Float16)f1.w;
            *(half8*)&As[row][c0 + c] = h;
            f0 = *(const float4*)&pb[c];
            f1 = *(const float4*)&pb[c + 4];
            h[0] = (_Float16)f0.x; h[1] = (_Float16)f0.y;
            h[2] = (_Float16)f0.z; h[3] = (_Float16)f0.w;
            h[4] = (_Float16)f1.x; h[5] = (_Float16)f1.y;
            h[6] = (_Float16)f1.z; h[7] = (_Float16)f1.w;
            *(half8*)&Bs[row][c0 + c] = h;
        }
    }
    if (tid < BT) clsA[tid] = classes[i0 + tid];
    else          clsB[tid - BT] = classes[j0 + tid - BT];
    __syncthreads();

    // each wave owns a 64x64 sub-tile: 4x4 grid of 16x16 MFMA tiles, K=128
    const int wave = tid >> 6;
    const int lane = tid & 63;
    const int wm = (wave >> 1) * 64;       // wave row offset in block tile
    const int wn = (wave & 1) * 64;        // wave col offset
    const int lr = lane & 15;              // operand non-K index
    const int quad = lane >> 4;
    const int ko = quad * 8;               // operand K offset

    floatx4 acc[4][4] = {};
    #pragma unroll
    for (int ks = 0; ks < 128; ks += 32) {
        half8 af[4], bf[4];
        #pragma unroll
        for (int mi = 0; mi < 4; ++mi)
            af[mi] = *(const half8*)&As[wm + mi * 16 + lr][ks + ko];
        #pragma unroll
        for (int ni = 0; ni < 4; ++ni)
            bf[ni] = *(const half8*)&Bs[wn + ni * 16 + lr][ks + ko];
        #pragma unroll
        for (int mi = 0; mi < 4; ++mi)
            #pragma unroll
            for (int ni = 0; ni < 4; ++ni)
                acc[mi][ni] = __builtin_amdgcn_mfma_f32_16x16x32_f16(
                    af[mi], bf[ni], acc[mi][ni], 0, 0, 0);
    }

    // classes for this lane's C fragment rows/cols
    int cA[4][4], cB[4];
    #pragma unroll
    for (int mi = 0; mi < 4; ++mi) {
        int4 c4 = *(const int4*)&clsA[wm + mi * 16 + quad * 4];
        cA[mi][0] = c4.x; cA[mi][1] = c4.y; cA[mi][2] = c4.z; cA[mi][3] = c4.w;
    }
    #pragma unroll
    for (int ni = 0; ni < 4; ++ni) cB[ni] = clsB[wn + ni * 16 + lr];

    // binning: C-layout col = lane&15, row = quad*4 + reg
    const int copy = lane & 31;
    const bool diag = (ti == tj);
    float* hb = &lhist[0][0];
    #pragma unroll
    for (int mi = 0; mi < 4; ++mi) {
        #pragma unroll
        for (int ni = 0; ni < 4; ++ni) {
            #pragma unroll
            for (int r = 0; r < 4; ++r) {
                const int li = wm + mi * 16 + quad * 4 + r;  // local row
                const int lj = wn + ni * 16 + lr;            // local col
                if (diag && li >= lj) continue;              // strict upper
                float s = acc[mi][ni][r];
                float pos = (s + 1.0f) * 50.0f;              // (s+1)/step
                int idx = (int)floorf(pos);
                idx = idx < 0 ? 0 : (idx > NBINS - 1 ? NBINS - 1 : idx);
                float frac = pos - (float)idx;
                int hoff = (cA[mi][r] == cB[ni]) ? 0 : NBINS;
                atomicAdd(&hb[(hoff + idx) * NCOPY + copy], 1.0f - frac);
                int up = idx + 1 > NBINS - 1 ? NBINS - 1 : idx + 1;
                atomicAdd(&hb[(hoff + up) * NCOPY + copy], frac);
            }
        }
    }
    __syncthreads();

    // merge 32 replicas -> global bins (rotated copy index: conflict-free)
    for (int t = tid; t < 2 * NBINS; t += NTHREADS) {
        float ssum = 0.0f;
        #pragma unroll
        for (int c = 0; c < NCOPY; ++c)
            ssum += lhist[t][(c + tid) & 31];
        atomicAdd(&g_hist[t], ssum);
    }
}

// ---------------------------------------------------------------------------
// normalize, cumsum(pos), dot with neg
// ---------------------------------------------------------------------------
__global__ void finalize_kernel(const float* __restrict__ g_hist,
                                float* __restrict__ out) {
    __shared__ float h[2 * NBINS];
    int tid = threadIdx.x;
    if (tid < 2 * NBINS) h[tid] = g_hist[tid];
    __syncthreads();
    if (tid == 0) {
        double sp = 0.0, sn = 0.0;
        for (int k = 0; k < NBINS; ++k) { sp += h[k]; sn += h[NBINS + k]; }
        double isp = 1.0 / sp, isn = 1.0 / sn;
        double cdf = 0.0, res = 0.0;
        for (int k = 0; k < NBINS; ++k) {
            cdf += (double)h[k] * isp;
            res += (double)h[NBINS + k] * isn * cdf;
        }
        out[0] = (float)res;
    }
}

extern "C" void kernel_launch(void* const* d_in, const int* in_sizes, int n_in,
                              void* d_out, int out_size, void* d_ws, size_t ws_size,
                              hipStream_t stream) {
    const float* feats   = (const float*)d_in[0];
    const int*   classes = (const int*)d_in[1];
    float* out    = (float*)d_out;
    float* g_hist = (float*)d_ws;

    int N = in_sizes[1];                       // 4096
    int ntiles = (N + BT - 1) / BT;            // 32
    int nblocks = ntiles * (ntiles + 1) / 2;   // 528

    hipMemsetAsync(d_ws, 0, 2 * NBINS * sizeof(float), stream);
    hist_pairs_kernel<<<nblocks, NTHREADS, 0, stream>>>(feats, classes, g_hist, ntiles);
    finalize_kernel<<<1, 256, 0, stream>>>(g_hist, out);
}

// Round 3
// 184.297 us; speedup vs baseline: 1.1437x; 1.1437x over previous
//
#include <hip/hip_runtime.h>

#define NBINS 101
#define BT 128            // block tile (pairs tile is BT x BT)
#define NTHREADS 256
#define NCOPY 16          // histogram replicas, one per lane&15

typedef _Float16 half8 __attribute__((ext_vector_type(8)));
typedef float floatx4 __attribute__((ext_vector_type(4)));

// ---------------------------------------------------------------------------
// One block per 128x128 upper-triangular tile. f16 MFMA computes the
// similarity tile; pairs are binned with NATIVE fp32 LDS atomics
// (unsafeAtomicAdd -> ds_add_f32; default atomicAdd lowers to a CAS loop,
// which round-2 counters implicate as the ~150us bottleneck). LDS tiles are
// K-major As[K/8][row][8] so fragment reads need no padding; total LDS
// ~79.5KB -> 2 blocks/CU. Last block to finish runs the finalize inline.
// ---------------------------------------------------------------------------
__global__ __launch_bounds__(NTHREADS, 2)
void hist_pairs_kernel(const float* __restrict__ feats,
                       const int* __restrict__ classes,
                       float* __restrict__ g_hist,     // [2*NBINS]
                       unsigned* __restrict__ g_count, // completion counter
                       float* __restrict__ out,
                       int ntiles, int nblocks) {
    __shared__ __align__(16) _Float16 As[16][BT][8];   // [K/8][row][8 halves]
    __shared__ __align__(16) _Float16 Bs[16][BT][8];
    __shared__ float lhist[2 * NBINS][NCOPY];
    __shared__ __align__(16) int clsA[BT];
    __shared__ __align__(16) int clsB[BT];
    __shared__ bool s_last;

    // blockIdx -> (ti, tj), ti <= tj, row-major over the upper triangle
    int b = blockIdx.x;
    int ti = 0, rem = b;
    while (rem >= ntiles - ti) { rem -= ntiles - ti; ++ti; }
    int tj = ti + rem;
    const int i0 = ti * BT, j0 = tj * BT;
    const int tid = threadIdx.x;

    // zero local histograms
    for (int t = tid; t < 2 * NBINS * NCOPY; t += NTHREADS)
        (&lhist[0][0])[t] = 0.0f;

    // stage both tiles fp32 -> f16, K-major chunks of 8
    {
        const int row = tid >> 1;
        const int c0 = (tid & 1) * 64;
        const float* pa = &feats[(size_t)(i0 + row) * 128 + c0];
        const float* pb = &feats[(size_t)(j0 + row) * 128 + c0];
        #pragma unroll
        for (int c = 0; c < 64; c += 8) {
            float4 f0 = *(const float4*)&pa[c];
            float4 f1 = *(const float4*)&pa[c + 4];
            half8 h;
            h[0] = (_Float16)f0.x; h[1] = (_Float16)f0.y;
            h[2] = (_Float16)f0.z; h[3] = (_Float16)f0.w;
            h[4] = (_Float16)f1.x; h[5] = (_Float16)f1.y;
            h[6] = (_Float16)f1.z; h[7] = (_Float16)f1.w;
            *(half8*)&As[(c0 + c) >> 3][row][0] = h;
            f0 = *(const float4*)&pb[c];
            f1 = *(const float4*)&pb[c + 4];
            h[0] = (_Float16)f0.x; h[1] = (_Float16)f0.y;
            h[2] = (_Float16)f0.z; h[3] = (_Float16)f0.w;
            h[4] = (_Float16)f1.x; h[5] = (_Float16)f1.y;
            h[6] = (_Float16)f1.z; h[7] = (_Float16)f1.w;
            *(half8*)&Bs[(c0 + c) >> 3][row][0] = h;
        }
    }
    if (tid < BT) clsA[tid] = classes[i0 + tid];
    else          clsB[tid - BT] = classes[j0 + tid - BT];
    __syncthreads();

    // each wave owns a 64x64 sub-tile: 4x4 grid of 16x16 MFMA tiles, K=128
    const int wave = tid >> 6;
    const int lane = tid & 63;
    const int wm = (wave >> 1) * 64;
    const int wn = (wave & 1) * 64;
    const int lr = lane & 15;
    const int quad = lane >> 4;

    floatx4 acc[4][4] = {};
    #pragma unroll
    for (int ks = 0; ks < 128; ks += 32) {
        half8 af[4], bf[4];
        #pragma unroll
        for (int mi = 0; mi < 4; ++mi)
            af[mi] = *(const half8*)&As[(ks >> 3) + quad][wm + mi * 16 + lr][0];
        #pragma unroll
        for (int ni = 0; ni < 4; ++ni)
            bf[ni] = *(const half8*)&Bs[(ks >> 3) + quad][wn + ni * 16 + lr][0];
        #pragma unroll
        for (int mi = 0; mi < 4; ++mi)
            #pragma unroll
            for (int ni = 0; ni < 4; ++ni)
                acc[mi][ni] = __builtin_amdgcn_mfma_f32_16x16x32_f16(
                    af[mi], bf[ni], acc[mi][ni], 0, 0, 0);
    }

    // classes for this lane's C fragment rows/cols
    int cA[4][4], cB[4];
    #pragma unroll
    for (int mi = 0; mi < 4; ++mi) {
        int4 c4 = *(const int4*)&clsA[wm + mi * 16 + quad * 4];
        cA[mi][0] = c4.x; cA[mi][1] = c4.y; cA[mi][2] = c4.z; cA[mi][3] = c4.w;
    }
    #pragma unroll
    for (int ni = 0; ni < 4; ++ni) cB[ni] = clsB[wn + ni * 16 + lr];

    // binning: C-layout col = lane&15, row = quad*4 + reg
    const int copy = lane & (NCOPY - 1);
    const bool diag = (ti == tj);
    #pragma unroll
    for (int mi = 0; mi < 4; ++mi) {
        #pragma unroll
        for (int ni = 0; ni < 4; ++ni) {
            #pragma unroll
            for (int r = 0; r < 4; ++r) {
                const int li = wm + mi * 16 + quad * 4 + r;
                const int lj = wn + ni * 16 + lr;
                if (diag && li >= lj) continue;  // strict upper triangle
                float s = acc[mi][ni][r];
                float pos = (s + 1.0f) * 50.0f;  // (s+1)/step, step=0.02
                int idx = (int)floorf(pos);
                idx = idx < 0 ? 0 : (idx > NBINS - 1 ? NBINS - 1 : idx);
                float frac = pos - (float)idx;
                int hoff = (cA[mi][r] == cB[ni]) ? 0 : NBINS;
                unsafeAtomicAdd(&lhist[hoff + idx][copy], 1.0f - frac);
                int up = idx + 1 > NBINS - 1 ? NBINS - 1 : idx + 1;
                unsafeAtomicAdd(&lhist[hoff + up][copy], frac);
            }
        }
    }
    __syncthreads();

    // merge replicas -> global bins (native fp32 global atomics)
    for (int t = tid; t < 2 * NBINS; t += NTHREADS) {
        float ssum = 0.0f;
        #pragma unroll
        for (int c = 0; c < NCOPY; ++c)
            ssum += lhist[t][(c + tid) & (NCOPY - 1)];
        unsafeAtomicAdd(&g_hist[t], ssum);
    }
    __syncthreads();

    // last block to finish runs the finalize
    if (tid == 0) {
        __threadfence();
        unsigned old = atomicAdd(g_count, 1u);
        s_last = (old == (unsigned)(nblocks - 1));
    }
    __syncthreads();
    if (!s_last) return;

    __threadfence();
    float* h = &lhist[0][0];   // reuse LDS
    if (tid < 2 * NBINS)
        h[tid] = __hip_atomic_load(&g_hist[tid], __ATOMIC_RELAXED,
                                   __HIP_MEMORY_SCOPE_AGENT);
    __syncthreads();
    if (tid == 0) {
        double sp = 0.0, sn = 0.0;
        for (int k = 0; k < NBINS; ++k) { sp += h[k]; sn += h[NBINS + k]; }
        double isp = 1.0 / sp, isn = 1.0 / sn;
        double cdf = 0.0, res = 0.0;
        for (int k = 0; k < NBINS; ++k) {
            cdf += (double)h[k] * isp;
            res += (double)h[NBINS + k] * isn * cdf;
        }
        out[0] = (float)res;
    }
}

extern "C" void kernel_launch(void* const* d_in, const int* in_sizes, int n_in,
                              void* d_out, int out_size, void* d_ws, size_t ws_size,
                              hipStream_t stream) {
    const float* feats   = (const float*)d_in[0];
    const int*   classes = (const int*)d_in[1];
    float* out      = (float*)d_out;
    float* g_hist   = (float*)d_ws;
    unsigned* g_cnt = (unsigned*)d_ws + 2 * NBINS;

    int N = in_sizes[1];                       // 4096
    int ntiles = (N + BT - 1) / BT;            // 32
    int nblocks = ntiles * (ntiles + 1) / 2;   // 528

    hipMemsetAsync(d_ws, 0, (2 * NBINS + 1) * sizeof(float), stream);
    hist_pairs_kernel<<<nblocks, NTHREADS, 0, stream>>>(
        feats, classes, g_hist, g_cnt, out, ntiles, nblocks);
}